// Round 3
// baseline (134.849 us; speedup 1.0000x reference)
//
#include <hip/hip_runtime.h>

#define NDOF 7
#define BLK 256
#define CST_STRIDE 24               // floats per dof block
#define CST_TOT (NDOF * CST_STRIDE) // 168

// ---------- tiny vec3 ----------
struct V3 { float x, y, z; };
__device__ __forceinline__ V3 operator+(V3 a, V3 b) { return {a.x + b.x, a.y + b.y, a.z + b.z}; }
__device__ __forceinline__ V3 operator-(V3 a, V3 b) { return {a.x - b.x, a.y - b.y, a.z - b.z}; }
__device__ __forceinline__ V3 operator*(float s, V3 a) { return {s * a.x, s * a.y, s * a.z}; }
__device__ __forceinline__ V3 cross(V3 a, V3 b) {
    return {a.y * b.z - a.z * b.y, a.z * b.x - a.x * b.z, a.x * b.y - a.y * b.x};
}
__device__ __forceinline__ float dot(V3 a, V3 b) { return a.x * b.x + a.y * b.y + a.z * b.z; }

// ---------- prep: pack per-dof constants into d_ws ----------
// per dof d (24 floats): [0:9) F columns (column-major), [9:12) p,
// [12:18) Io6=I00,I01,I02,I11,I12,I22, [18] m, [19:22) mc, [22] damp, [23] pad
__global__ void rnea_prep(const float* __restrict__ rot_fix,
                          const float* __restrict__ trans_fix,
                          const float* __restrict__ mass_g,
                          const float* __restrict__ com_g,
                          const float* __restrict__ inertia_g,
                          const float* __restrict__ damping_g,
                          float* __restrict__ cst) {
    const int d = threadIdx.x;
    if (d >= NDOF) return;
    float* o = cst + d * CST_STRIDE;
    const float* F = rot_fix + (1 + d) * 9;
#pragma unroll
    for (int j = 0; j < 3; j++)
#pragma unroll
        for (int i = 0; i < 3; i++) o[j * 3 + i] = F[i * 3 + j];  // column-major
#pragma unroll
    for (int i = 0; i < 3; i++) o[9 + i] = trans_fix[(1 + d) * 3 + i];
    const float m = mass_g[1 + d];
    const float c0 = com_g[(1 + d) * 3 + 0];
    const float c1 = com_g[(1 + d) * 3 + 1];
    const float c2 = com_g[(1 + d) * 3 + 2];
    const float* I = inertia_g + (1 + d) * 9;
    o[12] = I[0] + m * (c1 * c1 + c2 * c2);
    o[13] = I[1] - m * c0 * c1;
    o[14] = I[2] - m * c0 * c2;
    o[15] = I[4] + m * (c0 * c0 + c2 * c2);
    o[16] = I[5] - m * c1 * c2;
    o[17] = I[8] + m * (c0 * c0 + c1 * c1);
    o[18] = m;
    o[19] = m * c0;
    o[20] = m * c1;
    o[21] = m * c2;
    o[22] = damping_g[d];
    o[23] = 0.f;
}

// AX: 0 = +z, 1 = +y, 2 = -y   (joint_axes is a literal in the reference)
template <int AX>
__device__ __forceinline__ void make_R(V3 Fc0, V3 Fc1, V3 Fc2, float s, float c,
                                       V3& R0, V3& R1, V3& R2) {
    if (AX == 0) {          // Rq_z cols: (c,s,0), (-s,c,0), (0,0,1)
        R0 = c * Fc0 + s * Fc1;
        R1 = c * Fc1 - s * Fc0;
        R2 = Fc2;
    } else if (AX == 1) {   // Rq_y cols: (c,0,-s), (0,1,0), (s,0,c)
        R0 = c * Fc0 - s * Fc2;
        R1 = Fc1;
        R2 = s * Fc0 + c * Fc2;
    } else {                // Rq_-y cols: (c,0,s), (0,1,0), (-s,0,c)
        R0 = c * Fc0 + s * Fc2;
        R1 = Fc1;
        R2 = c * Fc2 - s * Fc0;
    }
}

// fwd: computes this link's fl/fa (local frame) and updates v/a state in place.
// Constants via uniform pointer + compile-time indices -> s_load (SGPRs).
template <int AX>
__device__ __forceinline__ void fwd_step(const float* __restrict__ C, float s, float c,
                                         float qd, float qdd, V3& vl, V3& va, V3& al,
                                         V3& aa, V3& fl, V3& fa) {
    const V3 Fc0{C[0], C[1], C[2]};
    const V3 Fc1{C[3], C[4], C[5]};
    const V3 Fc2{C[6], C[7], C[8]};
    const V3 p{C[9], C[10], C[11]};
    const float I00 = C[12], I01 = C[13], I02 = C[14], I11 = C[15], I12 = C[16], I22 = C[17];
    const float m = C[18];
    const V3 mc{C[19], C[20], C[21]};

    V3 R0, R1, R2;
    make_R<AX>(Fc0, Fc1, Fc2, s, c, R0, R1, R2);

    // Rt(vl) + cross(-Rt p, Rt va) == Rt(vl + va x p)
    V3 w1 = vl + cross(va, p);
    V3 w2 = al + cross(aa, p);
    V3 nvl{dot(R0, w1), dot(R1, w1), dot(R2, w1)};
    V3 nva{dot(R0, va), dot(R1, va), dot(R2, va)};
    V3 nal{dot(R0, w2), dot(R1, w2), dot(R2, w2)};
    V3 naa{dot(R0, aa), dot(R1, aa), dot(R2, aa)};

    if (AX == 0) {          // jv=(0,0,qd): cross(v,jv)=(v.y*qd,-v.x*qd,0)
        va = {nva.x, nva.y, nva.z + qd};
        aa = {naa.x + va.y * qd, naa.y - va.x * qd, naa.z + qdd};
        vl = nvl;
        al = {nal.x + vl.y * qd, nal.y - vl.x * qd, nal.z};
    } else if (AX == 1) {   // jv=(0,qd,0): cross(v,jv)=(-v.z*qd,0,v.x*qd)
        va = {nva.x, nva.y + qd, nva.z};
        aa = {naa.x - va.z * qd, naa.y + qdd, naa.z + va.x * qd};
        vl = nvl;
        al = {nal.x - vl.z * qd, nal.y, nal.z + vl.x * qd};
    } else {                // jv=(0,-qd,0): cross(v,jv)=(v.z*qd,0,-v.x*qd)
        va = {nva.x, nva.y - qd, nva.z};
        aa = {naa.x + va.z * qd, naa.y - qdd, naa.z - va.x * qd};
        vl = nvl;
        al = {nal.x + vl.z * qd, nal.y, nal.z - vl.x * qd};
    }

    V3 Ial = m * al + cross(aa, mc);
    V3 Iaa = V3{I00 * aa.x + I01 * aa.y + I02 * aa.z,
                I01 * aa.x + I11 * aa.y + I12 * aa.z,
                I02 * aa.x + I12 * aa.y + I22 * aa.z} + cross(mc, al);
    V3 Ivl = m * vl + cross(va, mc);
    V3 Iva = V3{I00 * va.x + I01 * va.y + I02 * va.z,
                I01 * va.x + I11 * va.y + I12 * va.z,
                I02 * va.x + I12 * va.y + I22 * va.z} + cross(mc, vl);
    fl = Ial + cross(va, Ivl);
    fa = Iaa + cross(va, Iva) + cross(vl, Ivl);
}

// bwd: consumes fl/fa by value (register-parked), updates carry, returns tau.
template <int AX>
__device__ __forceinline__ float bwd_core(const float* __restrict__ C, float s, float c,
                                          V3 fl, V3 fa, V3& cl, V3& ca) {
    const V3 Fc0{C[0], C[1], C[2]};
    const V3 Fc1{C[3], C[4], C[5]};
    const V3 Fc2{C[6], C[7], C[8]};
    const V3 p{C[9], C[10], C[11]};

    V3 tl = fl + cl;
    V3 ta = fa + ca;
    float tau;
    if (AX == 0) tau = ta.z;
    else if (AX == 1) tau = ta.y;
    else tau = -ta.y;

    V3 R0, R1, R2;
    make_R<AX>(Fc0, Fc1, Fc2, s, c, R0, R1, R2);
    V3 nl = tl.x * R0 + tl.y * R1 + tl.z * R2;   // R @ tl (columns)
    V3 na = ta.x * R0 + ta.y * R1 + ta.z * R2 + cross(p, nl);
    cl = nl;
    ca = na;
    return tau;
}

// ---------- main kernel ----------
// Dual-row O(n) RNEA: each thread runs TWO independent batch rows,
// interleaved at source level.  Rationale (round-2 counters): VALUBusy was
// pinned at 49% == single-dependent-chain issue ceiling (2 cyc issue / 4 cyc
// dep latency), and occupancy (~1-2 waves/SIMD at VGPR>=129) cannot rise
// because register pressure puts us in the 2-waves/SIMD bin regardless.  Two
// chains per wave give the scheduler back-to-back independent FMAs -> issue
// pipe fills without extra waves.  Constant s_loads are shared by both rows.
// Links 5,6 are fwd->bwd fused in registers so only links 0..4 park fl/fa
// (2 x 30 floats), keeping peak VGPR in the no-spill zone.
__global__ __launch_bounds__(BLK) void rnea_main(
    const float* __restrict__ q_g, const float* __restrict__ qd_g,
    const float* __restrict__ qdd_g, const float* __restrict__ cst,
    float* __restrict__ out, int nbatch) {
    const int t = threadIdx.x;
    const int halfn = (nbatch + 1) >> 1;
    const int rowA = blockIdx.x * BLK + t;
    const int rowB = rowA + halfn;
    const bool okA = rowA < nbatch;
    const bool okB = rowB < nbatch;
    const int rA = okA ? rowA : 0;
    const int rB = okB ? rowB : 0;
    const size_t goA = (size_t)rA * NDOF;
    const size_t goB = (size_t)rB * NDOF;

    float qdA[NDOF], qddA[NDOF], ssA[NDOF], ccA[NDOF];
    float qdB[NDOF], qddB[NDOF], ssB[NDOF], ccB[NDOF];
    {
        float qA[NDOF], qB[NDOF];
#pragma unroll
        for (int d = 0; d < NDOF; d++) qA[d] = q_g[goA + d];
#pragma unroll
        for (int d = 0; d < NDOF; d++) qB[d] = q_g[goB + d];
#pragma unroll
        for (int d = 0; d < NDOF; d++) qdA[d] = qd_g[goA + d];
#pragma unroll
        for (int d = 0; d < NDOF; d++) qdB[d] = qd_g[goB + d];
#pragma unroll
        for (int d = 0; d < NDOF; d++) qddA[d] = qdd_g[goA + d];
#pragma unroll
        for (int d = 0; d < NDOF; d++) qddB[d] = qdd_g[goB + d];
#pragma unroll
        for (int d = 0; d < NDOF; d++) { ssA[d] = __sinf(qA[d]); ccA[d] = __cosf(qA[d]); }
#pragma unroll
        for (int d = 0; d < NDOF; d++) { ssB[d] = __sinf(qB[d]); ccB[d] = __cosf(qB[d]); }
    }

    V3 vlA{0.f, 0.f, 0.f}, vaA{0.f, 0.f, 0.f}, alA{0.f, 0.f, 9.81f}, aaA{0.f, 0.f, 0.f};
    V3 vlB{0.f, 0.f, 0.f}, vaB{0.f, 0.f, 0.f}, alB{0.f, 0.f, 9.81f}, aaB{0.f, 0.f, 0.f};
    V3 flA0, faA0, flA1, faA1, flA2, faA2, flA3, faA3, flA4, faA4;
    V3 flB0, faB0, flB1, faB1, flB2, faB2, flB3, faB3, flB4, faB4;

    // axis sequence: z, y, z, -y, z, y, z -> AX ids 0,1,0,2,0,1,0
    // A/B calls interleaved per link: two independent chains share each
    // link's constants and fill the issue pipe.
    fwd_step<0>(cst + 0 * CST_STRIDE, ssA[0], ccA[0], qdA[0], qddA[0], vlA, vaA, alA, aaA, flA0, faA0);
    fwd_step<0>(cst + 0 * CST_STRIDE, ssB[0], ccB[0], qdB[0], qddB[0], vlB, vaB, alB, aaB, flB0, faB0);
    fwd_step<1>(cst + 1 * CST_STRIDE, ssA[1], ccA[1], qdA[1], qddA[1], vlA, vaA, alA, aaA, flA1, faA1);
    fwd_step<1>(cst + 1 * CST_STRIDE, ssB[1], ccB[1], qdB[1], qddB[1], vlB, vaB, alB, aaB, flB1, faB1);
    fwd_step<0>(cst + 2 * CST_STRIDE, ssA[2], ccA[2], qdA[2], qddA[2], vlA, vaA, alA, aaA, flA2, faA2);
    fwd_step<0>(cst + 2 * CST_STRIDE, ssB[2], ccB[2], qdB[2], qddB[2], vlB, vaB, alB, aaB, flB2, faB2);
    fwd_step<2>(cst + 3 * CST_STRIDE, ssA[3], ccA[3], qdA[3], qddA[3], vlA, vaA, alA, aaA, flA3, faA3);
    fwd_step<2>(cst + 3 * CST_STRIDE, ssB[3], ccB[3], qdB[3], qddB[3], vlB, vaB, alB, aaB, flB3, faB3);
    fwd_step<0>(cst + 4 * CST_STRIDE, ssA[4], ccA[4], qdA[4], qddA[4], vlA, vaA, alA, aaA, flA4, faA4);
    fwd_step<0>(cst + 4 * CST_STRIDE, ssB[4], ccB[4], qdB[4], qddB[4], vlB, vaB, alB, aaB, flB4, faB4);

    // links 5,6: fwd -> immediate bwd in registers (never parked)
    V3 flA5, faA5, flA6, faA6, flB5, faB5, flB6, faB6;
    fwd_step<1>(cst + 5 * CST_STRIDE, ssA[5], ccA[5], qdA[5], qddA[5], vlA, vaA, alA, aaA, flA5, faA5);
    fwd_step<1>(cst + 5 * CST_STRIDE, ssB[5], ccB[5], qdB[5], qddB[5], vlB, vaB, alB, aaB, flB5, faB5);
    fwd_step<0>(cst + 6 * CST_STRIDE, ssA[6], ccA[6], qdA[6], qddA[6], vlA, vaA, alA, aaA, flA6, faA6);
    fwd_step<0>(cst + 6 * CST_STRIDE, ssB[6], ccB[6], qdB[6], qddB[6], vlB, vaB, alB, aaB, flB6, faB6);

    V3 clA{0.f, 0.f, 0.f}, caA{0.f, 0.f, 0.f};
    V3 clB{0.f, 0.f, 0.f}, caB{0.f, 0.f, 0.f};
    float tauA[NDOF], tauB[NDOF];
    tauA[6] = bwd_core<0>(cst + 6 * CST_STRIDE, ssA[6], ccA[6], flA6, faA6, clA, caA);
    tauB[6] = bwd_core<0>(cst + 6 * CST_STRIDE, ssB[6], ccB[6], flB6, faB6, clB, caB);
    tauA[5] = bwd_core<1>(cst + 5 * CST_STRIDE, ssA[5], ccA[5], flA5, faA5, clA, caA);
    tauB[5] = bwd_core<1>(cst + 5 * CST_STRIDE, ssB[5], ccB[5], flB5, faB5, clB, caB);
    tauA[4] = bwd_core<0>(cst + 4 * CST_STRIDE, ssA[4], ccA[4], flA4, faA4, clA, caA);
    tauB[4] = bwd_core<0>(cst + 4 * CST_STRIDE, ssB[4], ccB[4], flB4, faB4, clB, caB);
    tauA[3] = bwd_core<2>(cst + 3 * CST_STRIDE, ssA[3], ccA[3], flA3, faA3, clA, caA);
    tauB[3] = bwd_core<2>(cst + 3 * CST_STRIDE, ssB[3], ccB[3], flB3, faB3, clB, caB);
    tauA[2] = bwd_core<0>(cst + 2 * CST_STRIDE, ssA[2], ccA[2], flA2, faA2, clA, caA);
    tauB[2] = bwd_core<0>(cst + 2 * CST_STRIDE, ssB[2], ccB[2], flB2, faB2, clB, caB);
    tauA[1] = bwd_core<1>(cst + 1 * CST_STRIDE, ssA[1], ccA[1], flA1, faA1, clA, caA);
    tauB[1] = bwd_core<1>(cst + 1 * CST_STRIDE, ssB[1], ccB[1], flB1, faB1, clB, caB);
    tauA[0] = bwd_core<0>(cst + 0 * CST_STRIDE, ssA[0], ccA[0], flA0, faA0, clA, caA);
    tauB[0] = bwd_core<0>(cst + 0 * CST_STRIDE, ssB[0], ccB[0], flB0, faB0, clB, caB);

    if (okA) {
#pragma unroll
        for (int d = 0; d < NDOF; d++)
            out[goA + d] = tauA[d] + cst[d * CST_STRIDE + 22] * qdA[d];
    }
    if (okB) {
#pragma unroll
        for (int d = 0; d < NDOF; d++)
            out[goB + d] = tauB[d] + cst[d * CST_STRIDE + 22] * qdB[d];
    }
}

extern "C" void kernel_launch(void* const* d_in, const int* in_sizes, int n_in,
                              void* d_out, int out_size, void* d_ws, size_t ws_size,
                              hipStream_t stream) {
    const float* q = (const float*)d_in[0];
    const float* qd = (const float*)d_in[1];
    const float* qdd = (const float*)d_in[2];
    const float* rot_fix = (const float*)d_in[3];
    const float* trans_fix = (const float*)d_in[4];
    // d_in[5] = joint_axes: compile-time constant in the reference (z,y,z,-y,z,y,z)
    const float* mass = (const float*)d_in[6];
    const float* com = (const float*)d_in[7];
    const float* inertia = (const float*)d_in[8];
    const float* damping = (const float*)d_in[9];
    float* out = (float*)d_out;
    float* cst = (float*)d_ws;  // 7*24*4 = 672 B

    const int n_elem = in_sizes[0];  // B * 7
    const int B = n_elem / NDOF;
    const int halfn = (B + 1) >> 1;
    const int grid = (halfn + BLK - 1) / BLK;

    rnea_prep<<<1, 64, 0, stream>>>(rot_fix, trans_fix, mass, com, inertia, damping, cst);
    rnea_main<<<grid, BLK, 0, stream>>>(q, qd, qdd, cst, out, B);
}